// Round 8
// baseline (423.105 us; speedup 1.0000x reference)
//
#include <hip/hip_runtime.h>
#include <hip/hip_bf16.h>
#include <math.h>

// ---------------------------------------------------------------------------
// Math note: softmax(A, axis=2) then sum(A, axis=2, keepdims=True) * V == V.
// Pipeline: X1 = LN(X + X@Wv + bv); out = LN(X1 + relu(X1@W1+b1)@W2 + b2)
//
// Round-8 (fixes round-7's two bugs):
//  (a) split-K partials now CONTIGUOUS at ws+0 (25.17MB); W2t moved past it.
//  (b) gemm256 counted vmcnt moved BEFORE the trailing barrier of phases 3/7
//      (vmcnt -> barrier -> ds_read ordering, as in the passing round-4/5).
//  - GEMM1 (8192x768x768): round-5 gemm128<96,1> (proven), grid 512
//  - GEMM2 (8192x3072x768): gemm256 8-phase, grid 384
//  - GEMM3 (8192x768x3072): gemm256 8-phase split-K x2, grid 192 -> ln_fuse2
// ---------------------------------------------------------------------------

typedef __bf16 bf16x8 __attribute__((ext_vector_type(8)));
typedef float f32x4 __attribute__((ext_vector_type(4)));

__device__ inline void gload_lds16(const __hip_bfloat16* g, void* lds) {
  __builtin_amdgcn_global_load_lds(
      (const __attribute__((address_space(1))) void*)g,
      (__attribute__((address_space(3))) void*)lds, 16, 0, 0);
}

__device__ inline float bf2f(unsigned short u) {
  union { unsigned int i; float f; } x;
  x.i = ((unsigned int)u) << 16;
  return x.f;
}

#define BARRIER() asm volatile("s_barrier" ::: "memory")

// ============================ gemm256 (8-phase) =============================
// C = A(MxK)@Bt(NxK)^T over K-range [z*Ksub,(z+1)*Ksub). 256x256 tile.
// EPI==0: raw bf16 partial at C+z*M*N; EPI==2: +bias relu -> bf16.
template <int EPI>
__global__ __launch_bounds__(512, 2) void gemm256(
    const __hip_bfloat16* __restrict__ A, const __hip_bfloat16* __restrict__ Bt,
    __hip_bfloat16* __restrict__ C, const float* __restrict__ bias,
    int M, int N, int K, int Ksub, int mB, int nB) {
  // LDS: A-slots[4] @0 (16KB each), B-slots[4] @65536
  __shared__ __align__(16) char smem[131072];

  const int bid = blockIdx.x;
  const int bpz = mB * nB;
  const int z = bid / bpz;
  const int rem = bid % bpz;
  const int rowBase = (rem % mB) * 256;  // row-fastest (L3-friendly)
  const int colBase = (rem / mB) * 256;
  const int kBase = z * Ksub;
  const int nt = Ksub / 64;  // even, >= 2

  const int wv = threadIdx.x >> 6;
  const int lane = threadIdx.x & 63;
  const int wr = wv >> 2;   // 0..1 : wave row-half (128 rows) == its A-half
  const int wc = wv & 3;    // 0..3 : 64-col block; B-half = wc>>1
  const int l16 = lane & 15, lk = lane >> 4;

  // staging source (pre-swizzled global: logical chunk = phys ^ (row&7))
  const int srow = lane >> 3;                        // 0..7
  const int scol = ((lane & 7) ^ srow) * 8;          // bf16 elements
  const __hip_bfloat16* gA =
      A + (size_t)(rowBase + srow) * K + kBase + scol;
  const __hip_bfloat16* gB =
      Bt + (size_t)(colBase + srow) * K + kBase + scol;

  // stage half h (128 rows x 64 cols) of K-tile tau into slot (2*tau+h)&3
  auto SA = [&](int tau, int h) {
    if (tau >= 2 && tau < nt) {
      const int slot = (2 * tau + h) & 3;
#pragma unroll
      for (int i = 0; i < 2; ++i)
        gload_lds16(gA + (size_t)(128 * h + 8 * (2 * wv + i)) * K +
                        (size_t)tau * 64,
                    smem + slot * 16384 + (wv * 2 + i) * 1024);
    }
  };
  auto SB = [&](int tau, int h) {
    if (tau >= 2 && tau < nt) {
      const int slot = (2 * tau + h) & 3;
#pragma unroll
      for (int i = 0; i < 2; ++i)
        gload_lds16(gB + (size_t)(128 * h + 8 * (2 * wv + i)) * K +
                        (size_t)tau * 64,
                    smem + 65536 + slot * 16384 + (wv * 2 + i) * 1024);
    }
  };

  // ds_read addressing: row byte = row*128; phys chunk = logical ^ (row&7)
  const int aOff = l16 * 128;
  const int bOff = (wc & 1) * 8192 + l16 * 128;
  const int cph0 = ((lk) ^ (l16 & 7)) * 16;
  const int cph1 = ((4 + lk) ^ (l16 & 7)) * 16;

  f32x4 acc[8][4];
#pragma unroll
  for (int m = 0; m < 8; ++m)
#pragma unroll
    for (int n = 0; n < 4; ++n) acc[m][n] = (f32x4){0.f, 0.f, 0.f, 0.f};

  bf16x8 bq0[4], bq1[4];  // B frags ks0 / ks1 (persist across phases)

  // prologue: stage K-tiles 0 (slots 0,1) then 1 (slots 2,3); wait tile 0;
  // vmcnt BEFORE barrier (correct ordering).
  {
#pragma unroll
    for (int tt = 0; tt < 2; ++tt) {
      const int s0 = 2 * tt;
#pragma unroll
      for (int h = 0; h < 2; ++h)
#pragma unroll
        for (int i = 0; i < 2; ++i)
          gload_lds16(gA + (size_t)(128 * h + 8 * (2 * wv + i)) * K +
                          (size_t)tt * 64,
                      smem + (s0 + h) * 16384 + (wv * 2 + i) * 1024);
#pragma unroll
      for (int h = 0; h < 2; ++h)
#pragma unroll
        for (int i = 0; i < 2; ++i)
          gload_lds16(gB + (size_t)(128 * h + 8 * (2 * wv + i)) * K +
                          (size_t)tt * 64,
                      smem + 65536 + (s0 + h) * 16384 + (wv * 2 + i) * 1024);
    }
    asm volatile("s_waitcnt vmcnt(8)" ::: "memory");
    BARRIER();
  }

// phase: K-tile T, m-half MH, slot CPH; READB loads B frags into BQ.
// STG: stage statement (issued before entry barrier).
// VM: counted vmcnt placed AFTER MFMA, BEFORE trailing barrier.
#define PH(T, MH, READB, BQ, CPH, STG, VM)                                   \
  {                                                                          \
    const char* pa_ = smem + (((2 * (T) + wr) & 3) * 16384) + aOff;          \
    bf16x8 af_[4];                                                           \
    _Pragma("unroll") for (int m_ = 0; m_ < 4; ++m_) af_[m_] =               \
        *(const bf16x8*)(pa_ + ((MH)*4 + m_) * 2048 + (CPH));                \
    if (READB) {                                                             \
      const char* pb_ =                                                      \
          smem + 65536 + (((2 * (T) + (wc >> 1)) & 3) * 16384) + bOff;       \
      _Pragma("unroll") for (int n_ = 0; n_ < 4; ++n_) BQ[n_] =              \
          *(const bf16x8*)(pb_ + n_ * 2048 + (CPH));                         \
    }                                                                        \
    STG;                                                                     \
    BARRIER();                                                               \
    asm volatile("s_waitcnt lgkmcnt(0)" ::: "memory");                       \
    __builtin_amdgcn_sched_barrier(0);                                       \
    __builtin_amdgcn_s_setprio(1);                                           \
    _Pragma("unroll") for (int m_ = 0; m_ < 4; ++m_) {                       \
      _Pragma("unroll") for (int n_ = 0; n_ < 4; ++n_) acc[(MH)*4 + m_][n_] =\
          __builtin_amdgcn_mfma_f32_16x16x32_bf16(af_[m_], BQ[n_],           \
                                                  acc[(MH)*4 + m_][n_], 0,   \
                                                  0, 0);                     \
    }                                                                        \
    __builtin_amdgcn_s_setprio(0);                                           \
    VM;                                                                      \
    BARRIER();                                                               \
  }

  const int iters = nt / 2;
  for (int i = 0; i < iters; ++i) {
    const int e = 2 * i, o = 2 * i + 1;
    // tile e: slots 0,1 (A and B rings); tile o: slots 2,3
    PH(e, 0, 1, bq0, cph0, SB(o, 1), (void)0);
    PH(e, 1, 0, bq0, cph0, SA(o, 0), (void)0);
    PH(e, 0, 1, bq1, cph1, SA(o, 1), (void)0);
    // end of phi3: tile-o readiness wait (leave only this phase's 2 stages)
    if (e + 2 < nt) {
      PH(e, 1, 0, bq1, cph1, SB(e + 2, 0),
         asm volatile("s_waitcnt vmcnt(2)" ::: "memory"));
    } else {
      PH(e, 1, 0, bq1, cph1, (void)0,
         asm volatile("s_waitcnt vmcnt(0)" ::: "memory"));
    }
    if (e + 2 < nt) {
      PH(o, 0, 1, bq0, cph0, SB(e + 2, 1), (void)0);
      PH(o, 1, 0, bq0, cph0, SA(e + 2, 0), (void)0);
      PH(o, 0, 1, bq1, cph1, SA(e + 2, 1), (void)0);
      // end of phi7: tile-(e+2) readiness wait
      PH(o, 1, 0, bq1, cph1, SB(o + 2, 0),
         asm volatile("s_waitcnt vmcnt(2)" ::: "memory"));
    } else {
      PH(o, 0, 1, bq0, cph0, (void)0, (void)0);
      PH(o, 1, 0, bq0, cph0, (void)0, (void)0);
      PH(o, 0, 1, bq1, cph1, (void)0, (void)0);
      PH(o, 1, 0, bq1, cph1, (void)0, (void)0);
    }
  }
#undef PH

  __hip_bfloat16* Cz = C + (size_t)z * M * N;
  // C/D layout: col=lane&15, row=(lane>>4)*4+reg (verified m89)
#pragma unroll
  for (int m = 0; m < 8; ++m) {
#pragma unroll
    for (int n = 0; n < 4; ++n) {
#pragma unroll
      for (int j = 0; j < 4; ++j) {
        const int r = rowBase + wr * 128 + m * 16 + lk * 4 + j;
        const int c = colBase + wc * 64 + n * 16 + l16;
        float v = acc[m][n][j];
        if (EPI == 2) v = fmaxf(v + bias[c], 0.f);
        Cz[(size_t)r * N + c] = __float2bfloat16(v);
      }
    }
  }
}

// ======================= gemm128 (round-5, for GEMM1) =======================
template <int BNv, int EPI>
__global__ __launch_bounds__(256, 2) void gemm128(
    const __hip_bfloat16* __restrict__ A, const __hip_bfloat16* __restrict__ Bt,
    __hip_bfloat16* __restrict__ C, const float* __restrict__ bias,
    const float* __restrict__ residf, const __hip_bfloat16* __restrict__ residb,
    int M, int N, int K) {
  constexpr int NF = BNv / 32;
  constexpr int BI = BNv / 32;
  constexpr int BS = BNv * 128;
  __shared__ __align__(16) char smem[32768 + 2 * BS];

  const int bid = blockIdx.x;
  const int mB = M / 128;
  const int rowBase = (bid % mB) * 128;
  const int colBase = (bid / mB) * BNv;
  const int nt = K / 64;

  const int wv = threadIdx.x >> 6;
  const int lane = threadIdx.x & 63;
  const int wr = wv >> 1, wc = wv & 1;
  const int l16 = lane & 15, lk = lane >> 4;

  const int rA = lane >> 3;
  const int cSw = ((lane & 7) ^ rA) * 8;
  const __hip_bfloat16* gA = A + (size_t)(rowBase + wv * 32 + rA) * K + cSw;
  const __hip_bfloat16* gB =
      Bt + (size_t)(colBase + wv * 8 * BI + rA) * K + cSw;

  auto STAGE = [&](int kt, int b) {
    const size_t ko = (size_t)kt * 64;
#pragma unroll
    for (int i = 0; i < 4; ++i)
      gload_lds16(gA + (size_t)i * 8 * K + ko,
                  smem + b * 16384 + (wv * 4 + i) * 1024);
#pragma unroll
    for (int i = 0; i < BI; ++i)
      gload_lds16(gB + (size_t)i * 8 * K + ko,
                  smem + 32768 + b * BS + (wv * BI + i) * 1024);
  };

  const int aBase = (wr * 64 + l16) * 128;
  const int bBase = (wc * (BNv / 2) + l16) * 128;
  const int xr = l16 & 7;
  const int cph0 = ((lk) ^ xr) * 16;
  const int cph1 = ((4 + lk) ^ xr) * 16;

  f32x4 acc[4][NF];
#pragma unroll
  for (int m = 0; m < 4; ++m)
#pragma unroll
    for (int n = 0; n < NF; ++n) acc[m][n] = (f32x4){0.f, 0.f, 0.f, 0.f};

  STAGE(0, 0);
  if (nt > 1) {
    STAGE(1, 1);
    if constexpr (BNv == 128)
      asm volatile("s_waitcnt vmcnt(8)" ::: "memory");
    else
      asm volatile("s_waitcnt vmcnt(7)" ::: "memory");
  } else {
    asm volatile("s_waitcnt vmcnt(0)" ::: "memory");
  }
  BARRIER();

  for (int t = 0; t < nt; ++t) {
    const int b = t & 1;
    const char* pa = smem + b * 16384 + aBase;
    const char* pb = smem + 32768 + b * BS + bBase;

    bf16x8 af0[4], af1[4], bf0[NF], bf1[NF];
#pragma unroll
    for (int m = 0; m < 4; ++m) af0[m] = *(const bf16x8*)(pa + m * 2048 + cph0);
#pragma unroll
    for (int n = 0; n < NF; ++n) bf0[n] = *(const bf16x8*)(pb + n * 2048 + cph0);
#pragma unroll
    for (int m = 0; m < 4; ++m) af1[m] = *(const bf16x8*)(pa + m * 2048 + cph1);
#pragma unroll
    for (int n = 0; n < NF; ++n) bf1[n] = *(const bf16x8*)(pb + n * 2048 + cph1);

    if constexpr (NF == 4)
      asm volatile("s_waitcnt lgkmcnt(8)" ::: "memory");
    else
      asm volatile("s_waitcnt lgkmcnt(7)" ::: "memory");
    __builtin_amdgcn_sched_barrier(0);
    __builtin_amdgcn_s_setprio(1);
#pragma unroll
    for (int m = 0; m < 4; ++m)
#pragma unroll
      for (int n = 0; n < NF; ++n)
        acc[m][n] = __builtin_amdgcn_mfma_f32_16x16x32_bf16(af0[m], bf0[n],
                                                            acc[m][n], 0, 0, 0);
    __builtin_amdgcn_s_setprio(0);
    asm volatile("s_waitcnt lgkmcnt(0)" ::: "memory");
    __builtin_amdgcn_sched_barrier(0);
    BARRIER();

    if (t + 2 < nt) STAGE(t + 2, b);

    __builtin_amdgcn_s_setprio(1);
#pragma unroll
    for (int m = 0; m < 4; ++m)
#pragma unroll
      for (int n = 0; n < NF; ++n)
        acc[m][n] = __builtin_amdgcn_mfma_f32_16x16x32_bf16(af1[m], bf1[n],
                                                            acc[m][n], 0, 0, 0);
    __builtin_amdgcn_s_setprio(0);

    if (t + 1 < nt) {
      if (t + 2 < nt) {
        if constexpr (BNv == 128)
          asm volatile("s_waitcnt vmcnt(8)" ::: "memory");
        else
          asm volatile("s_waitcnt vmcnt(7)" ::: "memory");
      } else {
        asm volatile("s_waitcnt vmcnt(0)" ::: "memory");
      }
      BARRIER();
    }
  }

#pragma unroll
  for (int m = 0; m < 4; ++m) {
#pragma unroll
    for (int n = 0; n < NF; ++n) {
#pragma unroll
      for (int j = 0; j < 4; ++j) {
        const int r = rowBase + wr * 64 + m * 16 + lk * 4 + j;
        const int c = colBase + wc * (BNv / 2) + n * 16 + l16;
        const size_t idx = (size_t)r * N + c;
        float v = acc[m][n][j] + bias[c];
        if (EPI == 1) v += residf[idx];
        if (EPI == 2) v = fmaxf(v, 0.f);
        if (EPI == 3) v += __bfloat162float(residb[idx]);
        C[idx] = __float2bfloat16(v);
      }
    }
  }
}

// ============================== LayerNorms ==================================
template <bool OUTF>
__global__ __launch_bounds__(256) void ln_simple(
    const __hip_bfloat16* __restrict__ Y, __hip_bfloat16* __restrict__ outb,
    float* __restrict__ outf) {
  const int wave = threadIdx.x >> 6, lane = threadIdx.x & 63;
  const size_t base = ((size_t)blockIdx.x * 4 + wave) * 768;

  float v[12];
  float s = 0.f, q = 0.f;
#pragma unroll
  for (int c = 0; c < 3; ++c) {
    const int col = c * 256 + lane * 4;
    ushort4 a = *reinterpret_cast<const ushort4*>(&Y[base + col]);
    float y0 = bf2f(a.x), y1 = bf2f(a.y), y2 = bf2f(a.z), y3 = bf2f(a.w);
    v[c * 4 + 0] = y0; v[c * 4 + 1] = y1; v[c * 4 + 2] = y2; v[c * 4 + 3] = y3;
    s += y0 + y1 + y2 + y3;
    q += y0 * y0 + y1 * y1 + y2 * y2 + y3 * y3;
  }
#pragma unroll
  for (int off = 32; off; off >>= 1) {
    s += __shfl_xor(s, off);
    q += __shfl_xor(q, off);
  }
  const float mu = s * (1.f / 768.f);
  const float rs = rsqrtf(q * (1.f / 768.f) - mu * mu);
#pragma unroll
  for (int c = 0; c < 3; ++c) {
    const int col = c * 256 + lane * 4;
    if (OUTF) {
      float4 o;
      o.x = (v[c * 4 + 0] - mu) * rs;
      o.y = (v[c * 4 + 1] - mu) * rs;
      o.z = (v[c * 4 + 2] - mu) * rs;
      o.w = (v[c * 4 + 3] - mu) * rs;
      *reinterpret_cast<float4*>(&outf[base + col]) = o;
    } else {
      __hip_bfloat16 h0 = __float2bfloat16((v[c * 4 + 0] - mu) * rs);
      __hip_bfloat16 h1 = __float2bfloat16((v[c * 4 + 1] - mu) * rs);
      __hip_bfloat16 h2 = __float2bfloat16((v[c * 4 + 2] - mu) * rs);
      __hip_bfloat16 h3 = __float2bfloat16((v[c * 4 + 3] - mu) * rs);
      ushort4 o;
      o.x = *reinterpret_cast<unsigned short*>(&h0);
      o.y = *reinterpret_cast<unsigned short*>(&h1);
      o.z = *reinterpret_cast<unsigned short*>(&h2);
      o.w = *reinterpret_cast<unsigned short*>(&h3);
      *reinterpret_cast<ushort4*>(&outb[base + col]) = o;
    }
  }
}

// Fused: y = P0 + P1 + resid(bf16) + bias; out = LN(y) -> fp32
__global__ __launch_bounds__(256) void ln_fuse2_final(
    const __hip_bfloat16* __restrict__ P0, const __hip_bfloat16* __restrict__ P1,
    const __hip_bfloat16* __restrict__ residb, const float* __restrict__ bias,
    float* __restrict__ outf) {
  const int wave = threadIdx.x >> 6, lane = threadIdx.x & 63;
  const size_t base = ((size_t)blockIdx.x * 4 + wave) * 768;

  float v[12];
  float s = 0.f, q = 0.f;
#pragma unroll
  for (int c = 0; c < 3; ++c) {
    const int col = c * 256 + lane * 4;
    ushort4 a = *reinterpret_cast<const ushort4*>(&P0[base + col]);
    ushort4 b = *reinterpret_cast<const ushort4*>(&P1[base + col]);
    ushort4 rb = *reinterpret_cast<const ushort4*>(&residb[base + col]);
    float4 bs = *reinterpret_cast<const float4*>(&bias[col]);
    float y0 = bf2f(a.x) + bf2f(b.x) + bf2f(rb.x) + bs.x;
    float y1 = bf2f(a.y) + bf2f(b.y) + bf2f(rb.y) + bs.y;
    float y2 = bf2f(a.z) + bf2f(b.z) + bf2f(rb.z) + bs.z;
    float y3 = bf2f(a.w) + bf2f(b.w) + bf2f(rb.w) + bs.w;
    v[c * 4 + 0] = y0; v[c * 4 + 1] = y1; v[c * 4 + 2] = y2; v[c * 4 + 3] = y3;
    s += y0 + y1 + y2 + y3;
    q += y0 * y0 + y1 * y1 + y2 * y2 + y3 * y3;
  }
#pragma unroll
  for (int off = 32; off; off >>= 1) {
    s += __shfl_xor(s, off);
    q += __shfl_xor(q, off);
  }
  const float mu = s * (1.f / 768.f);
  const float rs = rsqrtf(q * (1.f / 768.f) - mu * mu);
#pragma unroll
  for (int c = 0; c < 3; ++c) {
    const int col = c * 256 + lane * 4;
    float4 o;
    o.x = (v[c * 4 + 0] - mu) * rs;
    o.y = (v[c * 4 + 1] - mu) * rs;
    o.z = (v[c * 4 + 2] - mu) * rs;
    o.w = (v[c * 4 + 3] - mu) * rs;
    *reinterpret_cast<float4*>(&outf[base + col]) = o;
  }
}

// ============================ preprocessing ================================
__device__ inline void tc_tile(const float* __restrict__ W,
                               __hip_bfloat16* __restrict__ Wt, int K, int N,
                               int n0, int k0, int t) {
  __shared__ float tile[32][33];
  const int tx = t & 31;
  const int ty = t >> 5;
#pragma unroll
  for (int i = 0; i < 32; i += 8)
    tile[ty + i][tx] = W[(size_t)(k0 + ty + i) * N + n0 + tx];
  __syncthreads();
#pragma unroll
  for (int i = 0; i < 32; i += 8)
    Wt[(size_t)(n0 + ty + i) * K + k0 + tx] = __float2bfloat16(tile[tx][ty + i]);
}

__global__ __launch_bounds__(256) void prep_kernel(
    const float* __restrict__ X, const float* __restrict__ Wv,
    const float* __restrict__ W1, const float* __restrict__ W2,
    __hip_bfloat16* __restrict__ Xb, __hip_bfloat16* __restrict__ Wvt,
    __hip_bfloat16* __restrict__ W1t, __hip_bfloat16* __restrict__ W2t) {
  const int bid = blockIdx.x;
  const int t = threadIdx.x;
  if (bid < 6144) {
    const int i = bid * 256 + t;
    float4 v = reinterpret_cast<const float4*>(X)[i];
    __hip_bfloat16 h0 = __float2bfloat16(v.x), h1 = __float2bfloat16(v.y);
    __hip_bfloat16 h2 = __float2bfloat16(v.z), h3 = __float2bfloat16(v.w);
    ushort4 o;
    o.x = *reinterpret_cast<unsigned short*>(&h0);
    o.y = *reinterpret_cast<unsigned short*>(&h1);
    o.z = *reinterpret_cast<unsigned short*>(&h2);
    o.w = *reinterpret_cast<unsigned short*>(&h3);
    reinterpret_cast<ushort4*>(Xb)[i] = o;
  } else if (bid < 6720) {
    const int idx = bid - 6144;
    tc_tile(Wv, Wvt, 768, 768, (idx % 24) * 32, (idx / 24) * 32, t);
  } else if (bid < 9024) {
    const int idx = bid - 6720;
    tc_tile(W1, W1t, 768, 3072, (idx % 96) * 32, (idx / 96) * 32, t);
  } else {
    const int idx = bid - 9024;
    tc_tile(W2, W2t, 3072, 768, (idx % 24) * 32, (idx / 24) * 32, t);
  }
}

extern "C" void kernel_launch(void* const* d_in, const int* in_sizes, int n_in,
                              void* d_out, int out_size, void* d_ws,
                              size_t ws_size, hipStream_t stream) {
  const float* X = (const float*)d_in[0];
  const float* Wv = (const float*)d_in[5];
  const float* bv = (const float*)d_in[6];
  const float* W1 = (const float*)d_in[7];
  const float* b1 = (const float*)d_in[8];
  const float* W2 = (const float*)d_in[9];
  const float* b2 = (const float*)d_in[10];
  float* out = (float*)d_out;

  const int M = 4 * 2048;
  const int D = 768, H = 3072;

  // workspace layout (bytes), total 92,798,976:
  //  P3  @ 0 .. 25165824 (2 contiguous bf16 partials; spans dead Xb/Wvt/W1t)
  //    Xb  @ 0         (12,582,912) dead after GEMM1
  //    Wvt @ 12582912  ( 1,179,648) dead after GEMM1
  //    W1t @ 13762560  ( 4,718,592) dead after GEMM2
  //  W2t @ 25165824  ( 4,718,592)  live through GEMM3 (disjoint from P3!)
  //  X1b @ 29884416  (12,582,912)  live through LN2
  //  Gb  @ 42467328  (50,331,648)  written by GEMM2, read by GEMM3
  //    Yb @ 42467328 (12,582,912)  dead before GEMM2 writes Gb
  char* ws = (char*)d_ws;
  __hip_bfloat16* Xb  = (__hip_bfloat16*)(ws);
  __hip_bfloat16* Wvt = (__hip_bfloat16*)(ws + 12582912);
  __hip_bfloat16* W1t = (__hip_bfloat16*)(ws + 13762560);
  __hip_bfloat16* W2t = (__hip_bfloat16*)(ws + 25165824);
  __hip_bfloat16* X1b = (__hip_bfloat16*)(ws + 29884416);
  __hip_bfloat16* Gb  = (__hip_bfloat16*)(ws + 42467328);
  __hip_bfloat16* Yb  = (__hip_bfloat16*)(ws + 42467328);
  __hip_bfloat16* P3  = (__hip_bfloat16*)(ws);  // partial z at P3 + z*M*D

  prep_kernel<<<11328, 256, 0, stream>>>(X, Wv, W1, W2, Xb, Wvt, W1t, W2t);

  // Y = X@Wv + bv + X, grid 512 (round-5 proven)
  gemm128<96, 1><<<512, 256, 0, stream>>>(Xb, Wvt, Yb, bv, X, nullptr, M, D, D);
  // X1 = LN(Y)
  ln_simple<false><<<M / 4, 256, 0, stream>>>(Yb, X1b, nullptr);
  // G = relu(X1@W1 + b1): 8-phase 256^2, grid 32*12 = 384
  gemm256<2><<<384, 512, 0, stream>>>(X1b, W1t, Gb, b1, M, H, D, D, 32, 12);
  // P3[z] = Gb @ W2t (split-K x2): grid 32*3*2 = 192
  gemm256<0><<<192, 512, 0, stream>>>(Gb, W2t, P3, nullptr, M, D, H, H / 2,
                                      32, 3);
  // out = LN(P3_0 + P3_1 + X1 + b2)
  ln_fuse2_final<<<M / 4, 256, 0, stream>>>(P3, P3 + (size_t)M * D, X1b, b2,
                                            out);
}

// Round 9
// 421.553 us; speedup vs baseline: 1.0037x; 1.0037x over previous
//
#include <hip/hip_runtime.h>
#include <hip/hip_bf16.h>
#include <math.h>

// ---------------------------------------------------------------------------
// Math note: softmax(A, axis=2) then sum(A, axis=2, keepdims=True) * V == V.
// Pipeline: X1 = LN(X + X@Wv + bv); out = LN(X1 + relu(X1@W1+b1)@W2 + b2)
//
// Round-9: single change vs round-8: gemm256 __launch_bounds__(512) (was
// (512,2) which capped VGPR at 128 and spilled acc to scratch -> 380MB
// writes, MfmaUtil 0.2-7%). LDS=128KB already limits to 1 block/CU, so the
// min-waves bound was pure harm.
//  - GEMM1 (8192x768x768): gemm128<96,1> (proven), grid 512
//  - GEMM2 (8192x3072x768): gemm256 8-phase, grid 384
//  - GEMM3 (8192x768x3072): gemm256 8-phase split-K x2, grid 192 -> ln_fuse2
// ---------------------------------------------------------------------------

typedef __bf16 bf16x8 __attribute__((ext_vector_type(8)));
typedef float f32x4 __attribute__((ext_vector_type(4)));

__device__ inline void gload_lds16(const __hip_bfloat16* g, void* lds) {
  __builtin_amdgcn_global_load_lds(
      (const __attribute__((address_space(1))) void*)g,
      (__attribute__((address_space(3))) void*)lds, 16, 0, 0);
}

__device__ inline float bf2f(unsigned short u) {
  union { unsigned int i; float f; } x;
  x.i = ((unsigned int)u) << 16;
  return x.f;
}

#define BARRIER() asm volatile("s_barrier" ::: "memory")

// ============================ gemm256 (8-phase) =============================
// C = A(MxK)@Bt(NxK)^T over K-range [z*Ksub,(z+1)*Ksub). 256x256 tile.
// EPI==0: raw bf16 partial at C+z*M*N; EPI==2: +bias relu -> bf16.
template <int EPI>
__global__ __launch_bounds__(512) void gemm256(
    const __hip_bfloat16* __restrict__ A, const __hip_bfloat16* __restrict__ Bt,
    __hip_bfloat16* __restrict__ C, const float* __restrict__ bias,
    int M, int N, int K, int Ksub, int mB, int nB) {
  // LDS: A-slots[4] @0 (16KB each), B-slots[4] @65536
  __shared__ __align__(16) char smem[131072];

  const int bid = blockIdx.x;
  const int bpz = mB * nB;
  const int z = bid / bpz;
  const int rem = bid % bpz;
  const int rowBase = (rem % mB) * 256;  // row-fastest (L3-friendly)
  const int colBase = (rem / mB) * 256;
  const int kBase = z * Ksub;
  const int nt = Ksub / 64;  // even, >= 2

  const int wv = threadIdx.x >> 6;
  const int lane = threadIdx.x & 63;
  const int wr = wv >> 2;   // 0..1 : wave row-half (128 rows) == its A-half
  const int wc = wv & 3;    // 0..3 : 64-col block; B-half = wc>>1
  const int l16 = lane & 15, lk = lane >> 4;

  // staging source (pre-swizzled global: logical chunk = phys ^ (row&7))
  const int srow = lane >> 3;                        // 0..7
  const int scol = ((lane & 7) ^ srow) * 8;          // bf16 elements
  const __hip_bfloat16* gA =
      A + (size_t)(rowBase + srow) * K + kBase + scol;
  const __hip_bfloat16* gB =
      Bt + (size_t)(colBase + srow) * K + kBase + scol;

  // stage half h (128 rows x 64 cols) of K-tile tau into slot (2*tau+h)&3
  auto SA = [&](int tau, int h) {
    if (tau >= 2 && tau < nt) {
      const int slot = (2 * tau + h) & 3;
#pragma unroll
      for (int i = 0; i < 2; ++i)
        gload_lds16(gA + (size_t)(128 * h + 8 * (2 * wv + i)) * K +
                        (size_t)tau * 64,
                    smem + slot * 16384 + (wv * 2 + i) * 1024);
    }
  };
  auto SB = [&](int tau, int h) {
    if (tau >= 2 && tau < nt) {
      const int slot = (2 * tau + h) & 3;
#pragma unroll
      for (int i = 0; i < 2; ++i)
        gload_lds16(gB + (size_t)(128 * h + 8 * (2 * wv + i)) * K +
                        (size_t)tau * 64,
                    smem + 65536 + slot * 16384 + (wv * 2 + i) * 1024);
    }
  };

  // ds_read addressing: row byte = row*128; phys chunk = logical ^ (row&7)
  const int aOff = l16 * 128;
  const int bOff = (wc & 1) * 8192 + l16 * 128;
  const int cph0 = ((lk) ^ (l16 & 7)) * 16;
  const int cph1 = ((4 + lk) ^ (l16 & 7)) * 16;

  f32x4 acc[8][4];
#pragma unroll
  for (int m = 0; m < 8; ++m)
#pragma unroll
    for (int n = 0; n < 4; ++n) acc[m][n] = (f32x4){0.f, 0.f, 0.f, 0.f};

  bf16x8 bq0[4], bq1[4];  // B frags ks0 / ks1 (persist across phases)

  // prologue: stage K-tiles 0 (slots 0,1) then 1 (slots 2,3); wait tile 0;
  // vmcnt BEFORE barrier.
  {
#pragma unroll
    for (int tt = 0; tt < 2; ++tt) {
      const int s0 = 2 * tt;
#pragma unroll
      for (int h = 0; h < 2; ++h)
#pragma unroll
        for (int i = 0; i < 2; ++i)
          gload_lds16(gA + (size_t)(128 * h + 8 * (2 * wv + i)) * K +
                          (size_t)tt * 64,
                      smem + (s0 + h) * 16384 + (wv * 2 + i) * 1024);
#pragma unroll
      for (int h = 0; h < 2; ++h)
#pragma unroll
        for (int i = 0; i < 2; ++i)
          gload_lds16(gB + (size_t)(128 * h + 8 * (2 * wv + i)) * K +
                          (size_t)tt * 64,
                      smem + 65536 + (s0 + h) * 16384 + (wv * 2 + i) * 1024);
    }
    asm volatile("s_waitcnt vmcnt(8)" ::: "memory");
    BARRIER();
  }

// phase: K-tile T, m-half MH; READB loads B frags into BQ at chunk CPH.
// STG: stage statement (issued before entry barrier).
// VM: counted vmcnt placed AFTER MFMA, BEFORE trailing barrier.
#define PH(T, MH, READB, BQ, CPH, STG, VM)                                   \
  {                                                                          \
    const char* pa_ = smem + (((2 * (T) + wr) & 3) * 16384) + aOff;          \
    bf16x8 af_[4];                                                           \
    _Pragma("unroll") for (int m_ = 0; m_ < 4; ++m_) af_[m_] =               \
        *(const bf16x8*)(pa_ + ((MH)*4 + m_) * 2048 + (CPH));                \
    if (READB) {                                                             \
      const char* pb_ =                                                      \
          smem + 65536 + (((2 * (T) + (wc >> 1)) & 3) * 16384) + bOff;       \
      _Pragma("unroll") for (int n_ = 0; n_ < 4; ++n_) BQ[n_] =              \
          *(const bf16x8*)(pb_ + n_ * 2048 + (CPH));                         \
    }                                                                        \
    STG;                                                                     \
    BARRIER();                                                               \
    asm volatile("s_waitcnt lgkmcnt(0)" ::: "memory");                       \
    __builtin_amdgcn_sched_barrier(0);                                       \
    __builtin_amdgcn_s_setprio(1);                                           \
    _Pragma("unroll") for (int m_ = 0; m_ < 4; ++m_) {                       \
      _Pragma("unroll") for (int n_ = 0; n_ < 4; ++n_) acc[(MH)*4 + m_][n_] =\
          __builtin_amdgcn_mfma_f32_16x16x32_bf16(af_[m_], BQ[n_],           \
                                                  acc[(MH)*4 + m_][n_], 0,   \
                                                  0, 0);                     \
    }                                                                        \
    __builtin_amdgcn_s_setprio(0);                                           \
    VM;                                                                      \
    BARRIER();                                                               \
  }

  const int iters = nt / 2;
  for (int i = 0; i < iters; ++i) {
    const int e = 2 * i, o = 2 * i + 1;
    // tile e: A slots (2e+wr)&3, B slots (2e+bh)&3; tile o staged phases 0-2
    PH(e, 0, 1, bq0, cph0, SB(o, 1), (void)0);
    PH(e, 1, 0, bq0, cph0, SA(o, 0), (void)0);
    PH(e, 0, 1, bq1, cph1, SA(o, 1), (void)0);
    // end of phi3: tile-o readiness (leave only this phase's 2 stages)
    if (e + 2 < nt) {
      PH(e, 1, 0, bq1, cph1, SB(e + 2, 0),
         asm volatile("s_waitcnt vmcnt(2)" ::: "memory"));
    } else {
      PH(e, 1, 0, bq1, cph1, (void)0,
         asm volatile("s_waitcnt vmcnt(0)" ::: "memory"));
    }
    if (e + 2 < nt) {
      PH(o, 0, 1, bq0, cph0, SB(e + 2, 1), (void)0);
      PH(o, 1, 0, bq0, cph0, SA(e + 2, 0), (void)0);
      PH(o, 0, 1, bq1, cph1, SA(e + 2, 1), (void)0);
      // end of phi7: tile-(e+2) readiness
      PH(o, 1, 0, bq1, cph1, SB(o + 2, 0),
         asm volatile("s_waitcnt vmcnt(2)" ::: "memory"));
    } else {
      PH(o, 0, 1, bq0, cph0, (void)0, (void)0);
      PH(o, 1, 0, bq0, cph0, (void)0, (void)0);
      PH(o, 0, 1, bq1, cph1, (void)0, (void)0);
      PH(o, 1, 0, bq1, cph1, (void)0, (void)0);
    }
  }
#undef PH

  __hip_bfloat16* Cz = C + (size_t)z * M * N;
  // C/D layout: col=lane&15, row=(lane>>4)*4+reg (verified m89)
#pragma unroll
  for (int m = 0; m < 8; ++m) {
#pragma unroll
    for (int n = 0; n < 4; ++n) {
#pragma unroll
      for (int j = 0; j < 4; ++j) {
        const int r = rowBase + wr * 128 + m * 16 + lk * 4 + j;
        const int c = colBase + wc * 64 + n * 16 + l16;
        float v = acc[m][n][j];
        if (EPI == 2) v = fmaxf(v + bias[c], 0.f);
        Cz[(size_t)r * N + c] = __float2bfloat16(v);
      }
    }
  }
}

// ======================= gemm128 (round-5, for GEMM1) =======================
template <int BNv, int EPI>
__global__ __launch_bounds__(256, 2) void gemm128(
    const __hip_bfloat16* __restrict__ A, const __hip_bfloat16* __restrict__ Bt,
    __hip_bfloat16* __restrict__ C, const float* __restrict__ bias,
    const float* __restrict__ residf, const __hip_bfloat16* __restrict__ residb,
    int M, int N, int K) {
  constexpr int NF = BNv / 32;
  constexpr int BI = BNv / 32;
  constexpr int BS = BNv * 128;
  __shared__ __align__(16) char smem[32768 + 2 * BS];

  const int bid = blockIdx.x;
  const int mB = M / 128;
  const int rowBase = (bid % mB) * 128;
  const int colBase = (bid / mB) * BNv;
  const int nt = K / 64;

  const int wv = threadIdx.x >> 6;
  const int lane = threadIdx.x & 63;
  const int wr = wv >> 1, wc = wv & 1;
  const int l16 = lane & 15, lk = lane >> 4;

  const int rA = lane >> 3;
  const int cSw = ((lane & 7) ^ rA) * 8;
  const __hip_bfloat16* gA = A + (size_t)(rowBase + wv * 32 + rA) * K + cSw;
  const __hip_bfloat16* gB =
      Bt + (size_t)(colBase + wv * 8 * BI + rA) * K + cSw;

  auto STAGE = [&](int kt, int b) {
    const size_t ko = (size_t)kt * 64;
#pragma unroll
    for (int i = 0; i < 4; ++i)
      gload_lds16(gA + (size_t)i * 8 * K + ko,
                  smem + b * 16384 + (wv * 4 + i) * 1024);
#pragma unroll
    for (int i = 0; i < BI; ++i)
      gload_lds16(gB + (size_t)i * 8 * K + ko,
                  smem + 32768 + b * BS + (wv * BI + i) * 1024);
  };

  const int aBase = (wr * 64 + l16) * 128;
  const int bBase = (wc * (BNv / 2) + l16) * 128;
  const int xr = l16 & 7;
  const int cph0 = ((lk) ^ xr) * 16;
  const int cph1 = ((4 + lk) ^ xr) * 16;

  f32x4 acc[4][NF];
#pragma unroll
  for (int m = 0; m < 4; ++m)
#pragma unroll
    for (int n = 0; n < NF; ++n) acc[m][n] = (f32x4){0.f, 0.f, 0.f, 0.f};

  STAGE(0, 0);
  if (nt > 1) {
    STAGE(1, 1);
    if constexpr (BNv == 128)
      asm volatile("s_waitcnt vmcnt(8)" ::: "memory");
    else
      asm volatile("s_waitcnt vmcnt(7)" ::: "memory");
  } else {
    asm volatile("s_waitcnt vmcnt(0)" ::: "memory");
  }
  BARRIER();

  for (int t = 0; t < nt; ++t) {
    const int b = t & 1;
    const char* pa = smem + b * 16384 + aBase;
    const char* pb = smem + 32768 + b * BS + bBase;

    bf16x8 af0[4], af1[4], bf0[NF], bf1[NF];
#pragma unroll
    for (int m = 0; m < 4; ++m) af0[m] = *(const bf16x8*)(pa + m * 2048 + cph0);
#pragma unroll
    for (int n = 0; n < NF; ++n) bf0[n] = *(const bf16x8*)(pb + n * 2048 + cph0);
#pragma unroll
    for (int m = 0; m < 4; ++m) af1[m] = *(const bf16x8*)(pa + m * 2048 + cph1);
#pragma unroll
    for (int n = 0; n < NF; ++n) bf1[n] = *(const bf16x8*)(pb + n * 2048 + cph1);

    if constexpr (NF == 4)
      asm volatile("s_waitcnt lgkmcnt(8)" ::: "memory");
    else
      asm volatile("s_waitcnt lgkmcnt(7)" ::: "memory");
    __builtin_amdgcn_sched_barrier(0);
    __builtin_amdgcn_s_setprio(1);
#pragma unroll
    for (int m = 0; m < 4; ++m)
#pragma unroll
      for (int n = 0; n < NF; ++n)
        acc[m][n] = __builtin_amdgcn_mfma_f32_16x16x32_bf16(af0[m], bf0[n],
                                                            acc[m][n], 0, 0, 0);
    __builtin_amdgcn_s_setprio(0);
    asm volatile("s_waitcnt lgkmcnt(0)" ::: "memory");
    __builtin_amdgcn_sched_barrier(0);
    BARRIER();

    if (t + 2 < nt) STAGE(t + 2, b);

    __builtin_amdgcn_s_setprio(1);
#pragma unroll
    for (int m = 0; m < 4; ++m)
#pragma unroll
      for (int n = 0; n < NF; ++n)
        acc[m][n] = __builtin_amdgcn_mfma_f32_16x16x32_bf16(af1[m], bf1[n],
                                                            acc[m][n], 0, 0, 0);
    __builtin_amdgcn_s_setprio(0);

    if (t + 1 < nt) {
      if (t + 2 < nt) {
        if constexpr (BNv == 128)
          asm volatile("s_waitcnt vmcnt(8)" ::: "memory");
        else
          asm volatile("s_waitcnt vmcnt(7)" ::: "memory");
      } else {
        asm volatile("s_waitcnt vmcnt(0)" ::: "memory");
      }
      BARRIER();
    }
  }

#pragma unroll
  for (int m = 0; m < 4; ++m) {
#pragma unroll
    for (int n = 0; n < NF; ++n) {
#pragma unroll
      for (int j = 0; j < 4; ++j) {
        const int r = rowBase + wr * 64 + m * 16 + lk * 4 + j;
        const int c = colBase + wc * (BNv / 2) + n * 16 + l16;
        const size_t idx = (size_t)r * N + c;
        float v = acc[m][n][j] + bias[c];
        if (EPI == 1) v += residf[idx];
        if (EPI == 2) v = fmaxf(v, 0.f);
        if (EPI == 3) v += __bfloat162float(residb[idx]);
        C[idx] = __float2bfloat16(v);
      }
    }
  }
}

// ============================== LayerNorms ==================================
template <bool OUTF>
__global__ __launch_bounds__(256) void ln_simple(
    const __hip_bfloat16* __restrict__ Y, __hip_bfloat16* __restrict__ outb,
    float* __restrict__ outf) {
  const int wave = threadIdx.x >> 6, lane = threadIdx.x & 63;
  const size_t base = ((size_t)blockIdx.x * 4 + wave) * 768;

  float v[12];
  float s = 0.f, q = 0.f;
#pragma unroll
  for (int c = 0; c < 3; ++c) {
    const int col = c * 256 + lane * 4;
    ushort4 a = *reinterpret_cast<const ushort4*>(&Y[base + col]);
    float y0 = bf2f(a.x), y1 = bf2f(a.y), y2 = bf2f(a.z), y3 = bf2f(a.w);
    v[c * 4 + 0] = y0; v[c * 4 + 1] = y1; v[c * 4 + 2] = y2; v[c * 4 + 3] = y3;
    s += y0 + y1 + y2 + y3;
    q += y0 * y0 + y1 * y1 + y2 * y2 + y3 * y3;
  }
#pragma unroll
  for (int off = 32; off; off >>= 1) {
    s += __shfl_xor(s, off);
    q += __shfl_xor(q, off);
  }
  const float mu = s * (1.f / 768.f);
  const float rs = rsqrtf(q * (1.f / 768.f) - mu * mu);
#pragma unroll
  for (int c = 0; c < 3; ++c) {
    const int col = c * 256 + lane * 4;
    if (OUTF) {
      float4 o;
      o.x = (v[c * 4 + 0] - mu) * rs;
      o.y = (v[c * 4 + 1] - mu) * rs;
      o.z = (v[c * 4 + 2] - mu) * rs;
      o.w = (v[c * 4 + 3] - mu) * rs;
      *reinterpret_cast<float4*>(&outf[base + col]) = o;
    } else {
      __hip_bfloat16 h0 = __float2bfloat16((v[c * 4 + 0] - mu) * rs);
      __hip_bfloat16 h1 = __float2bfloat16((v[c * 4 + 1] - mu) * rs);
      __hip_bfloat16 h2 = __float2bfloat16((v[c * 4 + 2] - mu) * rs);
      __hip_bfloat16 h3 = __float2bfloat16((v[c * 4 + 3] - mu) * rs);
      ushort4 o;
      o.x = *reinterpret_cast<unsigned short*>(&h0);
      o.y = *reinterpret_cast<unsigned short*>(&h1);
      o.z = *reinterpret_cast<unsigned short*>(&h2);
      o.w = *reinterpret_cast<unsigned short*>(&h3);
      *reinterpret_cast<ushort4*>(&outb[base + col]) = o;
    }
  }
}

// Fused: y = P0 + P1 + resid(bf16) + bias; out = LN(y) -> fp32
__global__ __launch_bounds__(256) void ln_fuse2_final(
    const __hip_bfloat16* __restrict__ P0, const __hip_bfloat16* __restrict__ P1,
    const __hip_bfloat16* __restrict__ residb, const float* __restrict__ bias,
    float* __restrict__ outf) {
  const int wave = threadIdx.x >> 6, lane = threadIdx.x & 63;
  const size_t base = ((size_t)blockIdx.x * 4 + wave) * 768;

  float v[12];
  float s = 0.f, q = 0.f;
#pragma unroll
  for (int c = 0; c < 3; ++c) {
    const int col = c * 256 + lane * 4;
    ushort4 a = *reinterpret_cast<const ushort4*>(&P0[base + col]);
    ushort4 b = *reinterpret_cast<const ushort4*>(&P1[base + col]);
    ushort4 rb = *reinterpret_cast<const ushort4*>(&residb[base + col]);
    float4 bs = *reinterpret_cast<const float4*>(&bias[col]);
    float y0 = bf2f(a.x) + bf2f(b.x) + bf2f(rb.x) + bs.x;
    float y1 = bf2f(a.y) + bf2f(b.y) + bf2f(rb.y) + bs.y;
    float y2 = bf2f(a.z) + bf2f(b.z) + bf2f(rb.z) + bs.z;
    float y3 = bf2f(a.w) + bf2f(b.w) + bf2f(rb.w) + bs.w;
    v[c * 4 + 0] = y0; v[c * 4 + 1] = y1; v[c * 4 + 2] = y2; v[c * 4 + 3] = y3;
    s += y0 + y1 + y2 + y3;
    q += y0 * y0 + y1 * y1 + y2 * y2 + y3 * y3;
  }
#pragma unroll
  for (int off = 32; off; off >>= 1) {
    s += __shfl_xor(s, off);
    q += __shfl_xor(q, off);
  }
  const float mu = s * (1.f / 768.f);
  const float rs = rsqrtf(q * (1.f / 768.f) - mu * mu);
#pragma unroll
  for (int c = 0; c < 3; ++c) {
    const int col = c * 256 + lane * 4;
    float4 o;
    o.x = (v[c * 4 + 0] - mu) * rs;
    o.y = (v[c * 4 + 1] - mu) * rs;
    o.z = (v[c * 4 + 2] - mu) * rs;
    o.w = (v[c * 4 + 3] - mu) * rs;
    *reinterpret_cast<float4*>(&outf[base + col]) = o;
  }
}

// ============================ preprocessing ================================
__device__ inline void tc_tile(const float* __restrict__ W,
                               __hip_bfloat16* __restrict__ Wt, int K, int N,
                               int n0, int k0, int t) {
  __shared__ float tile[32][33];
  const int tx = t & 31;
  const int ty = t >> 5;
#pragma unroll
  for (int i = 0; i < 32; i += 8)
    tile[ty + i][tx] = W[(size_t)(k0 + ty + i) * N + n0 + tx];
  __syncthreads();
#pragma unroll
  for (int i = 0; i < 32; i += 8)
    Wt[(size_t)(n0 + ty + i) * K + k0 + tx] = __float2bfloat16(tile[tx][ty + i]);
}

__global__ __launch_bounds__(256) void prep_kernel(
    const float* __restrict__ X, const float* __restrict__ Wv,
    const float* __restrict__ W1, const float* __restrict__ W2,
    __hip_bfloat16* __restrict__ Xb, __hip_bfloat16* __restrict__ Wvt,
    __hip_bfloat16* __restrict__ W1t, __hip_bfloat16* __restrict__ W2t) {
  const int bid = blockIdx.x;
  const int t = threadIdx.x;
  if (bid < 6144) {
    const int i = bid * 256 + t;
    float4 v = reinterpret_cast<const float4*>(X)[i];
    __hip_bfloat16 h0 = __float2bfloat16(v.x), h1 = __float2bfloat16(v.y);
    __hip_bfloat16 h2 = __float2bfloat16(v.z), h3 = __float2bfloat16(v.w);
    ushort4 o;
    o.x = *reinterpret_cast<unsigned short*>(&h0);
    o.y = *reinterpret_cast<unsigned short*>(&h1);
    o.z = *reinterpret_cast<unsigned short*>(&h2);
    o.w = *reinterpret_cast<unsigned short*>(&h3);
    reinterpret_cast<ushort4*>(Xb)[i] = o;
  } else if (bid < 6720) {
    const int idx = bid - 6144;
    tc_tile(Wv, Wvt, 768, 768, (idx % 24) * 32, (idx / 24) * 32, t);
  } else if (bid < 9024) {
    const int idx = bid - 6720;
    tc_tile(W1, W1t, 768, 3072, (idx % 96) * 32, (idx / 96) * 32, t);
  } else {
    const int idx = bid - 9024;
    tc_tile(W2, W2t, 3072, 768, (idx % 24) * 32, (idx / 24) * 32, t);
  }
}

extern "C" void kernel_launch(void* const* d_in, const int* in_sizes, int n_in,
                              void* d_out, int out_size, void* d_ws,
                              size_t ws_size, hipStream_t stream) {
  const float* X = (const float*)d_in[0];
  const float* Wv = (const float*)d_in[5];
  const float* bv = (const float*)d_in[6];
  const float* W1 = (const float*)d_in[7];
  const float* b1 = (const float*)d_in[8];
  const float* W2 = (const float*)d_in[9];
  const float* b2 = (const float*)d_in[10];
  float* out = (float*)d_out;

  const int M = 4 * 2048;
  const int D = 768, H = 3072;

  // workspace layout (bytes), total 92,798,976:
  //  P3  @ 0 .. 25165824 (2 contiguous bf16 partials; spans dead Xb/Wvt/W1t)
  //    Xb  @ 0         (12,582,912) dead after GEMM1
  //    Wvt @ 12582912  ( 1,179,648) dead after GEMM1
  //    W1t @ 13762560  ( 4,718,592) dead after GEMM2
  //  W2t @ 25165824  ( 4,718,592)  live through GEMM3 (disjoint from P3)
  //  X1b @ 29884416  (12,582,912)  live through LN2
  //  Gb  @ 42467328  (50,331,648)  written by GEMM2, read by GEMM3
  //    Yb @ 42467328 (12,582,912)  dead before GEMM2 writes Gb
  char* ws = (char*)d_ws;
  __hip_bfloat16* Xb  = (__hip_bfloat16*)(ws);
  __hip_bfloat16* Wvt = (__hip_bfloat16*)(ws + 12582912);
  __hip_bfloat16* W1t = (__hip_bfloat16*)(ws + 13762560);
  __hip_bfloat16* W2t = (__hip_bfloat16*)(ws + 25165824);
  __hip_bfloat16* X1b = (__hip_bfloat16*)(ws + 29884416);
  __hip_bfloat16* Gb  = (__hip_bfloat16*)(ws + 42467328);
  __hip_bfloat16* Yb  = (__hip_bfloat16*)(ws + 42467328);
  __hip_bfloat16* P3  = (__hip_bfloat16*)(ws);  // partial z at P3 + z*M*D

  prep_kernel<<<11328, 256, 0, stream>>>(X, Wv, W1, W2, Xb, Wvt, W1t, W2t);

  // Y = X@Wv + bv + X, grid 512 (round-5 proven)
  gemm128<96, 1><<<512, 256, 0, stream>>>(Xb, Wvt, Yb, bv, X, nullptr, M, D, D);
  // X1 = LN(Y)
  ln_simple<false><<<M / 4, 256, 0, stream>>>(Yb, X1b, nullptr);
  // G = relu(X1@W1 + b1): 8-phase 256^2, grid 32*12 = 384
  gemm256<2><<<384, 512, 0, stream>>>(X1b, W1t, Gb, b1, M, H, D, D, 32, 12);
  // P3[z] = Gb @ W2t (split-K x2): grid 32*3*2 = 192
  gemm256<0><<<192, 512, 0, stream>>>(Gb, W2t, P3, nullptr, M, D, H, H / 2,
                                      32, 3);
  // out = LN(P3_0 + P3_1 + X1 + b2)
  ln_fuse2_final<<<M / 4, 256, 0, stream>>>(P3, P3 + (size_t)M * D, X1b, b2,
                                            out);
}

// Round 10
// 282.126 us; speedup vs baseline: 1.4997x; 1.4942x over previous
//
#include <hip/hip_runtime.h>
#include <hip/hip_bf16.h>
#include <math.h>

// ---------------------------------------------------------------------------
// Math note: softmax(A, axis=2) then sum(A, axis=2, keepdims=True) * V == V.
// Pipeline: X1 = LN(X + X@Wv + bv); out = LN(X1 + relu(X1@W1+b1)@W2 + b2)
//
// Round-10: gemm256 gets __launch_bounds__(512, 1) — rounds 8/9 showed the
// compiler's DEFAULT budget for 8-wave blocks caps unified regs at 256/wave
// (VGPR_Count=128 + spilled acc -> 378MB scratch writes, MfmaUtil 7%).
// min-waves=1 lifts the cap (LDS=128KB already forces 1 block/CU anyway).
// Risk bounded: gemm256 used ONLY for GEMM2; GEMM3 back to proven gemm128.
//  - GEMM1 (8192x768x768):  gemm128<96,1>, grid 512   (round-5 proven)
//  - GEMM2 (8192x3072x768): gemm256 8-phase, grid 384 (the experiment)
//  - GEMM3 (8192x768x3072): gemm128<96,3>, grid 512   (round-5 proven)
// ---------------------------------------------------------------------------

typedef __bf16 bf16x8 __attribute__((ext_vector_type(8)));
typedef float f32x4 __attribute__((ext_vector_type(4)));

__device__ inline void gload_lds16(const __hip_bfloat16* g, void* lds) {
  __builtin_amdgcn_global_load_lds(
      (const __attribute__((address_space(1))) void*)g,
      (__attribute__((address_space(3))) void*)lds, 16, 0, 0);
}

__device__ inline float bf2f(unsigned short u) {
  union { unsigned int i; float f; } x;
  x.i = ((unsigned int)u) << 16;
  return x.f;
}

#define BARRIER() asm volatile("s_barrier" ::: "memory")

// ============================ gemm256 (8-phase) =============================
// C = A(MxK)@Bt(NxK)^T, 256x256 tile. EPI==2: +bias relu -> bf16.
template <int EPI>
__global__ __launch_bounds__(512, 1) void gemm256(
    const __hip_bfloat16* __restrict__ A, const __hip_bfloat16* __restrict__ Bt,
    __hip_bfloat16* __restrict__ C, const float* __restrict__ bias,
    int M, int N, int K, int mB, int nB) {
  // LDS: A-slots[4] @0 (16KB each), B-slots[4] @65536
  __shared__ __align__(16) char smem[131072];

  const int bid = blockIdx.x;
  const int rowBase = (bid % mB) * 256;  // row-fastest (L3-friendly)
  const int colBase = (bid / mB) * 256;
  const int nt = K / 64;  // even, >= 4

  const int wv = threadIdx.x >> 6;
  const int lane = threadIdx.x & 63;
  const int wr = wv >> 2;   // 0..1 : wave row-half (128 rows) == its A-half
  const int wc = wv & 3;    // 0..3 : 64-col block; B-half = wc>>1
  const int l16 = lane & 15, lk = lane >> 4;

  // staging source (pre-swizzled global: logical chunk = phys ^ (row&7))
  const int srow = lane >> 3;                // 0..7
  const int scol = ((lane & 7) ^ srow) * 8;  // bf16 elements
  const __hip_bfloat16* gA = A + (size_t)(rowBase + srow) * K + scol;
  const __hip_bfloat16* gB = Bt + (size_t)(colBase + srow) * K + scol;

  // stage half h (128 rows x 64 cols) of K-tile tau into slot (2*tau+h)&3
  auto SA = [&](int tau, int h) {
    if (tau >= 2 && tau < nt) {
      const int slot = (2 * tau + h) & 3;
#pragma unroll
      for (int i = 0; i < 2; ++i)
        gload_lds16(gA + (size_t)(128 * h + 8 * (2 * wv + i)) * K +
                        (size_t)tau * 64,
                    smem + slot * 16384 + (wv * 2 + i) * 1024);
    }
  };
  auto SB = [&](int tau, int h) {
    if (tau >= 2 && tau < nt) {
      const int slot = (2 * tau + h) & 3;
#pragma unroll
      for (int i = 0; i < 2; ++i)
        gload_lds16(gB + (size_t)(128 * h + 8 * (2 * wv + i)) * K +
                        (size_t)tau * 64,
                    smem + 65536 + slot * 16384 + (wv * 2 + i) * 1024);
    }
  };

  // ds_read addressing: row byte = row*128; phys chunk = logical ^ (row&7)
  const int aOff = l16 * 128;
  const int bOff = (wc & 1) * 8192 + l16 * 128;
  const int cph0 = ((lk) ^ (l16 & 7)) * 16;
  const int cph1 = ((4 + lk) ^ (l16 & 7)) * 16;

  f32x4 acc[8][4];
#pragma unroll
  for (int m = 0; m < 8; ++m)
#pragma unroll
    for (int n = 0; n < 4; ++n) acc[m][n] = (f32x4){0.f, 0.f, 0.f, 0.f};

  bf16x8 bq0[4], bq1[4];  // B frags ks0 / ks1 (persist across phases)

  // prologue: stage K-tiles 0 (slots 0,1) then 1 (slots 2,3); wait tile 0.
  {
#pragma unroll
    for (int tt = 0; tt < 2; ++tt) {
      const int s0 = 2 * tt;
#pragma unroll
      for (int h = 0; h < 2; ++h)
#pragma unroll
        for (int i = 0; i < 2; ++i)
          gload_lds16(gA + (size_t)(128 * h + 8 * (2 * wv + i)) * K +
                          (size_t)tt * 64,
                      smem + (s0 + h) * 16384 + (wv * 2 + i) * 1024);
#pragma unroll
      for (int h = 0; h < 2; ++h)
#pragma unroll
        for (int i = 0; i < 2; ++i)
          gload_lds16(gB + (size_t)(128 * h + 8 * (2 * wv + i)) * K +
                          (size_t)tt * 64,
                      smem + 65536 + (s0 + h) * 16384 + (wv * 2 + i) * 1024);
    }
    asm volatile("s_waitcnt vmcnt(8)" ::: "memory");
    BARRIER();
  }

// phase: K-tile T, m-half MH; READB loads B frags into BQ at chunk CPH.
// STG: stage statement. VM: counted vmcnt AFTER MFMA, BEFORE trailing barrier.
#define PH(T, MH, READB, BQ, CPH, STG, VM)                                   \
  {                                                                          \
    const char* pa_ = smem + (((2 * (T) + wr) & 3) * 16384) + aOff;          \
    bf16x8 af_[4];                                                           \
    _Pragma("unroll") for (int m_ = 0; m_ < 4; ++m_) af_[m_] =               \
        *(const bf16x8*)(pa_ + ((MH)*4 + m_) * 2048 + (CPH));                \
    if (READB) {                                                             \
      const char* pb_ =                                                      \
          smem + 65536 + (((2 * (T) + (wc >> 1)) & 3) * 16384) + bOff;       \
      _Pragma("unroll") for (int n_ = 0; n_ < 4; ++n_) BQ[n_] =              \
          *(const bf16x8*)(pb_ + n_ * 2048 + (CPH));                         \
    }                                                                        \
    STG;                                                                     \
    BARRIER();                                                               \
    asm volatile("s_waitcnt lgkmcnt(0)" ::: "memory");                       \
    __builtin_amdgcn_sched_barrier(0);                                       \
    __builtin_amdgcn_s_setprio(1);                                           \
    _Pragma("unroll") for (int m_ = 0; m_ < 4; ++m_) {                       \
      _Pragma("unroll") for (int n_ = 0; n_ < 4; ++n_) acc[(MH)*4 + m_][n_] =\
          __builtin_amdgcn_mfma_f32_16x16x32_bf16(af_[m_], BQ[n_],           \
                                                  acc[(MH)*4 + m_][n_], 0,   \
                                                  0, 0);                     \
    }                                                                        \
    __builtin_amdgcn_s_setprio(0);                                           \
    VM;                                                                      \
    BARRIER();                                                               \
  }

  const int iters = nt / 2;
  for (int i = 0; i < iters; ++i) {
    const int e = 2 * i, o = 2 * i + 1;
    PH(e, 0, 1, bq0, cph0, SB(o, 1), (void)0);
    PH(e, 1, 0, bq0, cph0, SA(o, 0), (void)0);
    PH(e, 0, 1, bq1, cph1, SA(o, 1), (void)0);
    // end of phi3: tile-o readiness (leave only this phase's 2 stages)
    if (e + 2 < nt) {
      PH(e, 1, 0, bq1, cph1, SB(e + 2, 0),
         asm volatile("s_waitcnt vmcnt(2)" ::: "memory"));
    } else {
      PH(e, 1, 0, bq1, cph1, (void)0,
         asm volatile("s_waitcnt vmcnt(0)" ::: "memory"));
    }
    if (e + 2 < nt) {
      PH(o, 0, 1, bq0, cph0, SB(e + 2, 1), (void)0);
      PH(o, 1, 0, bq0, cph0, SA(e + 2, 0), (void)0);
      PH(o, 0, 1, bq1, cph1, SA(e + 2, 1), (void)0);
      // end of phi7: tile-(e+2) readiness
      PH(o, 1, 0, bq1, cph1, SB(o + 2, 0),
         asm volatile("s_waitcnt vmcnt(2)" ::: "memory"));
    } else {
      PH(o, 0, 1, bq0, cph0, (void)0, (void)0);
      PH(o, 1, 0, bq0, cph0, (void)0, (void)0);
      PH(o, 0, 1, bq1, cph1, (void)0, (void)0);
      PH(o, 1, 0, bq1, cph1, (void)0, (void)0);
    }
  }
#undef PH

  // C/D layout: col=lane&15, row=(lane>>4)*4+reg (verified m89)
#pragma unroll
  for (int m = 0; m < 8; ++m) {
#pragma unroll
    for (int n = 0; n < 4; ++n) {
#pragma unroll
      for (int j = 0; j < 4; ++j) {
        const int r = rowBase + wr * 128 + m * 16 + lk * 4 + j;
        const int c = colBase + wc * 64 + n * 16 + l16;
        float v = acc[m][n][j];
        if (EPI == 2) v = fmaxf(v + bias[c], 0.f);
        C[(size_t)r * N + c] = __float2bfloat16(v);
      }
    }
  }
}

// ======================= gemm128 (round-5 proven) ==========================
template <int BNv, int EPI>
__global__ __launch_bounds__(256, 2) void gemm128(
    const __hip_bfloat16* __restrict__ A, const __hip_bfloat16* __restrict__ Bt,
    __hip_bfloat16* __restrict__ C, const float* __restrict__ bias,
    const float* __restrict__ residf, const __hip_bfloat16* __restrict__ residb,
    int M, int N, int K) {
  constexpr int NF = BNv / 32;
  constexpr int BI = BNv / 32;
  constexpr int BS = BNv * 128;
  __shared__ __align__(16) char smem[32768 + 2 * BS];

  const int bid = blockIdx.x;
  const int mB = M / 128;
  const int rowBase = (bid % mB) * 128;
  const int colBase = (bid / mB) * BNv;
  const int nt = K / 64;

  const int wv = threadIdx.x >> 6;
  const int lane = threadIdx.x & 63;
  const int wr = wv >> 1, wc = wv & 1;
  const int l16 = lane & 15, lk = lane >> 4;

  const int rA = lane >> 3;
  const int cSw = ((lane & 7) ^ rA) * 8;
  const __hip_bfloat16* gA = A + (size_t)(rowBase + wv * 32 + rA) * K + cSw;
  const __hip_bfloat16* gB =
      Bt + (size_t)(colBase + wv * 8 * BI + rA) * K + cSw;

  auto STAGE = [&](int kt, int b) {
    const size_t ko = (size_t)kt * 64;
#pragma unroll
    for (int i = 0; i < 4; ++i)
      gload_lds16(gA + (size_t)i * 8 * K + ko,
                  smem + b * 16384 + (wv * 4 + i) * 1024);
#pragma unroll
    for (int i = 0; i < BI; ++i)
      gload_lds16(gB + (size_t)i * 8 * K + ko,
                  smem + 32768 + b * BS + (wv * BI + i) * 1024);
  };

  const int aBase = (wr * 64 + l16) * 128;
  const int bBase = (wc * (BNv / 2) + l16) * 128;
  const int xr = l16 & 7;
  const int cph0 = ((lk) ^ xr) * 16;
  const int cph1 = ((4 + lk) ^ xr) * 16;

  f32x4 acc[4][NF];
#pragma unroll
  for (int m = 0; m < 4; ++m)
#pragma unroll
    for (int n = 0; n < NF; ++n) acc[m][n] = (f32x4){0.f, 0.f, 0.f, 0.f};

  STAGE(0, 0);
  if (nt > 1) {
    STAGE(1, 1);
    if constexpr (BNv == 128)
      asm volatile("s_waitcnt vmcnt(8)" ::: "memory");
    else
      asm volatile("s_waitcnt vmcnt(7)" ::: "memory");
  } else {
    asm volatile("s_waitcnt vmcnt(0)" ::: "memory");
  }
  BARRIER();

  for (int t = 0; t < nt; ++t) {
    const int b = t & 1;
    const char* pa = smem + b * 16384 + aBase;
    const char* pb = smem + 32768 + b * BS + bBase;

    bf16x8 af0[4], af1[4], bf0[NF], bf1[NF];
#pragma unroll
    for (int m = 0; m < 4; ++m) af0[m] = *(const bf16x8*)(pa + m * 2048 + cph0);
#pragma unroll
    for (int n = 0; n < NF; ++n) bf0[n] = *(const bf16x8*)(pb + n * 2048 + cph0);
#pragma unroll
    for (int m = 0; m < 4; ++m) af1[m] = *(const bf16x8*)(pa + m * 2048 + cph1);
#pragma unroll
    for (int n = 0; n < NF; ++n) bf1[n] = *(const bf16x8*)(pb + n * 2048 + cph1);

    if constexpr (NF == 4)
      asm volatile("s_waitcnt lgkmcnt(8)" ::: "memory");
    else
      asm volatile("s_waitcnt lgkmcnt(7)" ::: "memory");
    __builtin_amdgcn_sched_barrier(0);
    __builtin_amdgcn_s_setprio(1);
#pragma unroll
    for (int m = 0; m < 4; ++m)
#pragma unroll
      for (int n = 0; n < NF; ++n)
        acc[m][n] = __builtin_amdgcn_mfma_f32_16x16x32_bf16(af0[m], bf0[n],
                                                            acc[m][n], 0, 0, 0);
    __builtin_amdgcn_s_setprio(0);
    asm volatile("s_waitcnt lgkmcnt(0)" ::: "memory");
    __builtin_amdgcn_sched_barrier(0);
    BARRIER();

    if (t + 2 < nt) STAGE(t + 2, b);

    __builtin_amdgcn_s_setprio(1);
#pragma unroll
    for (int m = 0; m < 4; ++m)
#pragma unroll
      for (int n = 0; n < NF; ++n)
        acc[m][n] = __builtin_amdgcn_mfma_f32_16x16x32_bf16(af1[m], bf1[n],
                                                            acc[m][n], 0, 0, 0);
    __builtin_amdgcn_s_setprio(0);

    if (t + 1 < nt) {
      if (t + 2 < nt) {
        if constexpr (BNv == 128)
          asm volatile("s_waitcnt vmcnt(8)" ::: "memory");
        else
          asm volatile("s_waitcnt vmcnt(7)" ::: "memory");
      } else {
        asm volatile("s_waitcnt vmcnt(0)" ::: "memory");
      }
      BARRIER();
    }
  }

#pragma unroll
  for (int m = 0; m < 4; ++m) {
#pragma unroll
    for (int n = 0; n < NF; ++n) {
#pragma unroll
      for (int j = 0; j < 4; ++j) {
        const int r = rowBase + wr * 64 + m * 16 + lk * 4 + j;
        const int c = colBase + wc * (BNv / 2) + n * 16 + l16;
        const size_t idx = (size_t)r * N + c;
        float v = acc[m][n][j] + bias[c];
        if (EPI == 1) v += residf[idx];
        if (EPI == 2) v = fmaxf(v, 0.f);
        if (EPI == 3) v += __bfloat162float(residb[idx]);
        C[idx] = __float2bfloat16(v);
      }
    }
  }
}

// ============================== LayerNorm ==================================
template <bool OUTF>
__global__ __launch_bounds__(256) void ln_simple(
    const __hip_bfloat16* __restrict__ Y, __hip_bfloat16* __restrict__ outb,
    float* __restrict__ outf) {
  const int wave = threadIdx.x >> 6, lane = threadIdx.x & 63;
  const size_t base = ((size_t)blockIdx.x * 4 + wave) * 768;

  float v[12];
  float s = 0.f, q = 0.f;
#pragma unroll
  for (int c = 0; c < 3; ++c) {
    const int col = c * 256 + lane * 4;
    ushort4 a = *reinterpret_cast<const ushort4*>(&Y[base + col]);
    float y0 = bf2f(a.x), y1 = bf2f(a.y), y2 = bf2f(a.z), y3 = bf2f(a.w);
    v[c * 4 + 0] = y0; v[c * 4 + 1] = y1; v[c * 4 + 2] = y2; v[c * 4 + 3] = y3;
    s += y0 + y1 + y2 + y3;
    q += y0 * y0 + y1 * y1 + y2 * y2 + y3 * y3;
  }
#pragma unroll
  for (int off = 32; off; off >>= 1) {
    s += __shfl_xor(s, off);
    q += __shfl_xor(q, off);
  }
  const float mu = s * (1.f / 768.f);
  const float rs = rsqrtf(q * (1.f / 768.f) - mu * mu);
#pragma unroll
  for (int c = 0; c < 3; ++c) {
    const int col = c * 256 + lane * 4;
    if (OUTF) {
      float4 o;
      o.x = (v[c * 4 + 0] - mu) * rs;
      o.y = (v[c * 4 + 1] - mu) * rs;
      o.z = (v[c * 4 + 2] - mu) * rs;
      o.w = (v[c * 4 + 3] - mu) * rs;
      *reinterpret_cast<float4*>(&outf[base + col]) = o;
    } else {
      __hip_bfloat16 h0 = __float2bfloat16((v[c * 4 + 0] - mu) * rs);
      __hip_bfloat16 h1 = __float2bfloat16((v[c * 4 + 1] - mu) * rs);
      __hip_bfloat16 h2 = __float2bfloat16((v[c * 4 + 2] - mu) * rs);
      __hip_bfloat16 h3 = __float2bfloat16((v[c * 4 + 3] - mu) * rs);
      ushort4 o;
      o.x = *reinterpret_cast<unsigned short*>(&h0);
      o.y = *reinterpret_cast<unsigned short*>(&h1);
      o.z = *reinterpret_cast<unsigned short*>(&h2);
      o.w = *reinterpret_cast<unsigned short*>(&h3);
      *reinterpret_cast<ushort4*>(&outb[base + col]) = o;
    }
  }
}

// ============================ preprocessing ================================
__device__ inline void tc_tile(const float* __restrict__ W,
                               __hip_bfloat16* __restrict__ Wt, int K, int N,
                               int n0, int k0, int t) {
  __shared__ float tile[32][33];
  const int tx = t & 31;
  const int ty = t >> 5;
#pragma unroll
  for (int i = 0; i < 32; i += 8)
    tile[ty + i][tx] = W[(size_t)(k0 + ty + i) * N + n0 + tx];
  __syncthreads();
#pragma unroll
  for (int i = 0; i < 32; i += 8)
    Wt[(size_t)(n0 + ty + i) * K + k0 + tx] = __float2bfloat16(tile[tx][ty + i]);
}

__global__ __launch_bounds__(256) void prep_kernel(
    const float* __restrict__ X, const float* __restrict__ Wv,
    const float* __restrict__ W1, const float* __restrict__ W2,
    __hip_bfloat16* __restrict__ Xb, __hip_bfloat16* __restrict__ Wvt,
    __hip_bfloat16* __restrict__ W1t, __hip_bfloat16* __restrict__ W2t) {
  const int bid = blockIdx.x;
  const int t = threadIdx.x;
  if (bid < 6144) {
    const int i = bid * 256 + t;
    float4 v = reinterpret_cast<const float4*>(X)[i];
    __hip_bfloat16 h0 = __float2bfloat16(v.x), h1 = __float2bfloat16(v.y);
    __hip_bfloat16 h2 = __float2bfloat16(v.z), h3 = __float2bfloat16(v.w);
    ushort4 o;
    o.x = *reinterpret_cast<unsigned short*>(&h0);
    o.y = *reinterpret_cast<unsigned short*>(&h1);
    o.z = *reinterpret_cast<unsigned short*>(&h2);
    o.w = *reinterpret_cast<unsigned short*>(&h3);
    reinterpret_cast<ushort4*>(Xb)[i] = o;
  } else if (bid < 6720) {
    const int idx = bid - 6144;
    tc_tile(Wv, Wvt, 768, 768, (idx % 24) * 32, (idx / 24) * 32, t);
  } else if (bid < 9024) {
    const int idx = bid - 6720;
    tc_tile(W1, W1t, 768, 3072, (idx % 96) * 32, (idx / 96) * 32, t);
  } else {
    const int idx = bid - 9024;
    tc_tile(W2, W2t, 3072, 768, (idx % 24) * 32, (idx / 24) * 32, t);
  }
}

extern "C" void kernel_launch(void* const* d_in, const int* in_sizes, int n_in,
                              void* d_out, int out_size, void* d_ws,
                              size_t ws_size, hipStream_t stream) {
  const float* X = (const float*)d_in[0];
  const float* Wv = (const float*)d_in[5];
  const float* bv = (const float*)d_in[6];
  const float* W1 = (const float*)d_in[7];
  const float* b1 = (const float*)d_in[8];
  const float* W2 = (const float*)d_in[9];
  const float* b2 = (const float*)d_in[10];
  float* out = (float*)d_out;

  const int M = 4 * 2048;
  const int D = 768, H = 3072;

  // workspace layout (round-5 proven), total 98,697,216:
  //  Xb   @ 0         (12,582,912)
  //  Wvt  @ 12582912  ( 1,179,648)
  //  W1t  @ 13762560  ( 4,718,592)
  //  W2t  @ 18481152  ( 4,718,592)
  //  Yb   @ 23199744  (12,582,912)   (reused as Y2b after LN1)
  //  X1b  @ 35782656  (12,582,912)
  //  Gb   @ 48365568  (50,331,648)
  char* ws = (char*)d_ws;
  __hip_bfloat16* Xb  = (__hip_bfloat16*)(ws);
  __hip_bfloat16* Wvt = (__hip_bfloat16*)(ws + 12582912);
  __hip_bfloat16* W1t = (__hip_bfloat16*)(ws + 13762560);
  __hip_bfloat16* W2t = (__hip_bfloat16*)(ws + 18481152);
  __hip_bfloat16* Yb  = (__hip_bfloat16*)(ws + 23199744);
  __hip_bfloat16* X1b = (__hip_bfloat16*)(ws + 35782656);
  __hip_bfloat16* Gb  = (__hip_bfloat16*)(ws + 48365568);
  __hip_bfloat16* Y2b = Yb;  // Yb dead after LN1

  prep_kernel<<<11328, 256, 0, stream>>>(X, Wv, W1, W2, Xb, Wvt, W1t, W2t);

  // Y = X@Wv + bv + X  (fused residual), grid 512
  gemm128<96, 1><<<512, 256, 0, stream>>>(Xb, Wvt, Yb, bv, X, nullptr, M, D, D);
  // X1 = LN(Y)
  ln_simple<false><<<M / 4, 256, 0, stream>>>(Yb, X1b, nullptr);
  // G = relu(X1@W1 + b1): 8-phase 256^2, grid 32*12 = 384
  gemm256<2><<<384, 512, 0, stream>>>(X1b, W1t, Gb, b1, M, H, D, 32, 12);
  // Y2 = G@W2 + b2 + X1 (fused residual), grid 512, nt=48
  gemm128<96, 3><<<512, 256, 0, stream>>>(Gb, W2t, Y2b, b2, nullptr, X1b, M, D,
                                          H);
  // out = LN(Y2)
  ln_simple<true><<<M / 4, 256, 0, stream>>>(Y2b, nullptr, out);
}

// Round 11
// 120.902 us; speedup vs baseline: 3.4996x; 2.3335x over previous
//
#include <hip/hip_runtime.h>
#include <hip/hip_bf16.h>
#include <math.h>

// ---------------------------------------------------------------------------
// Math note: softmax(A, axis=2) then sum(A, axis=2, keepdims=True) * V == V.
// Pipeline: X1 = LN(X + X@Wv + bv); out = LN(X1 + relu(X1@W1+b1)@W2 + b2)
//
// Round-11 = round-5 (125.3us proven) + low-risk tweaks:
//  - gemm256 abandoned (3x identical spill on this toolchain: VGPR capped 128,
//    380MB scratch writes regardless of launch_bounds).
//  - GEMM2: BN=192 (427 B LDS-read per MFMA vs 512; grid 1024 = 2 exact
//    rounds @ 2 blocks/CU; LDS 80KB = exactly 2 blocks/CU).
//  - GEMM1: Y = X@(Wv+I) + bv  (diagonal folded in prep; epilogue bias-only,
//    drops 25MB fp32 residual stream).
//  - GEMM3: gemm128<96,3>, grid 512, nt=48 (round-5 proven).
// ---------------------------------------------------------------------------

typedef __bf16 bf16x8 __attribute__((ext_vector_type(8)));
typedef float f32x4 __attribute__((ext_vector_type(4)));

__device__ inline void gload_lds16(const __hip_bfloat16* g, void* lds) {
  __builtin_amdgcn_global_load_lds(
      (const __attribute__((address_space(1))) void*)g,
      (__attribute__((address_space(3))) void*)lds, 16, 0, 0);
}

__device__ inline float bf2f(unsigned short u) {
  union { unsigned int i; float f; } x;
  x.i = ((unsigned int)u) << 16;
  return x.f;
}

#define BARRIER() asm volatile("s_barrier" ::: "memory")

template <int N>
__device__ __forceinline__ void vmwait() {
  if constexpr (N == 0)
    asm volatile("s_waitcnt vmcnt(0)" ::: "memory");
  else if constexpr (N == 7)
    asm volatile("s_waitcnt vmcnt(7)" ::: "memory");
  else if constexpr (N == 8)
    asm volatile("s_waitcnt vmcnt(8)" ::: "memory");
  else if constexpr (N == 10)
    asm volatile("s_waitcnt vmcnt(10)" ::: "memory");
}

template <int N>
__device__ __forceinline__ void lgwait() {
  if constexpr (N == 0)
    asm volatile("s_waitcnt lgkmcnt(0)" ::: "memory");
  else if constexpr (N == 7)
    asm volatile("s_waitcnt lgkmcnt(7)" ::: "memory");
  else if constexpr (N == 8)
    asm volatile("s_waitcnt lgkmcnt(8)" ::: "memory");
  else if constexpr (N == 10)
    asm volatile("s_waitcnt lgkmcnt(10)" ::: "memory");
}

// C(MxN) = A(MxK) @ Bt(NxK)^T, 128 x BNv tile, BK=64, 4 waves (2x2).
// EPI==2: +bias relu; EPI==3: +bias +bf16 residual; EPI==4: +bias only.
template <int BNv, int EPI>
__global__ __launch_bounds__(256, 2) void gemm128(
    const __hip_bfloat16* __restrict__ A, const __hip_bfloat16* __restrict__ Bt,
    __hip_bfloat16* __restrict__ C, const float* __restrict__ bias,
    const __hip_bfloat16* __restrict__ residb, int M, int N, int K) {
  constexpr int NF = BNv / 32;   // n-frags per wave (3, 4, or 6)
  constexpr int BI = BNv / 32;   // B stage instrs per wave
  constexpr int BS = BNv * 128;  // bytes per B buffer
  constexpr int S = 4 + BI;      // stage instrs per wave per K-tile
  // smem: A0[16K] A1[16K] B0[BS] B1[BS]
  __shared__ __align__(16) char smem[32768 + 2 * BS];

  const int bid = blockIdx.x;
  const int mB = M / 128;
  const int rowBase = (bid % mB) * 128;  // row-fastest (L3-friendly)
  const int colBase = (bid / mB) * BNv;
  const int nt = K / 64;

  const int wv = threadIdx.x >> 6;
  const int lane = threadIdx.x & 63;
  const int wr = wv >> 1, wc = wv & 1;   // 2x2 waves
  const int l16 = lane & 15, lk = lane >> 4;

  // staging map (pre-swizzled global source, linear LDS dest; rule 21)
  const int rA = lane >> 3;               // 0..7 row within 8-row stripe
  const int cSw = ((lane & 7) ^ rA) * 8;  // logical col = phys ^ (row&7)
  const __hip_bfloat16* gA = A + (size_t)(rowBase + wv * 32 + rA) * K + cSw;
  const __hip_bfloat16* gB =
      Bt + (size_t)(colBase + wv * 8 * BI + rA) * K + cSw;

  auto STAGE = [&](int kt, int b) {
    const size_t ko = (size_t)kt * 64;
#pragma unroll
    for (int i = 0; i < 4; ++i)
      gload_lds16(gA + (size_t)i * 8 * K + ko,
                  smem + b * 16384 + (wv * 4 + i) * 1024);
#pragma unroll
    for (int i = 0; i < BI; ++i)
      gload_lds16(gB + (size_t)i * 8 * K + ko,
                  smem + 32768 + b * BS + (wv * BI + i) * 1024);
  };

  // ds_read addressing (swizzled chunk: phys = logical ^ (row&7))
  const int aBase = (wr * 64 + l16) * 128;
  const int bBase = (wc * (BNv / 2) + l16) * 128;
  const int xr = l16 & 7;
  const int cph0 = ((lk) ^ xr) * 16;
  const int cph1 = ((4 + lk) ^ xr) * 16;

  f32x4 acc[4][NF];
#pragma unroll
  for (int m = 0; m < 4; ++m)
#pragma unroll
    for (int n = 0; n < NF; ++n) acc[m][n] = (f32x4){0.f, 0.f, 0.f, 0.f};

  STAGE(0, 0);
  if (nt > 1) {
    STAGE(1, 1);
    vmwait<S>();
  } else {
    vmwait<0>();
  }
  BARRIER();

  for (int t = 0; t < nt; ++t) {
    const int b = t & 1;
    const char* pa = smem + b * 16384 + aBase;
    const char* pb = smem + 32768 + b * BS + bBase;

    bf16x8 af0[4], af1[4], bf0[NF], bf1[NF];
#pragma unroll
    for (int m = 0; m < 4; ++m) af0[m] = *(const bf16x8*)(pa + m * 2048 + cph0);
#pragma unroll
    for (int n = 0; n < NF; ++n) bf0[n] = *(const bf16x8*)(pb + n * 2048 + cph0);
#pragma unroll
    for (int m = 0; m < 4; ++m) af1[m] = *(const bf16x8*)(pa + m * 2048 + cph1);
#pragma unroll
    for (int n = 0; n < NF; ++n) bf1[n] = *(const bf16x8*)(pb + n * 2048 + cph1);

    // ks0 frags ready when only the (4+NF) ks1 reads remain (in-order DS)
    lgwait<S>();
    __builtin_amdgcn_sched_barrier(0);
    __builtin_amdgcn_s_setprio(1);
#pragma unroll
    for (int m = 0; m < 4; ++m)
#pragma unroll
      for (int n = 0; n < NF; ++n)
        acc[m][n] = __builtin_amdgcn_mfma_f32_16x16x32_bf16(af0[m], bf0[n],
                                                            acc[m][n], 0, 0, 0);
    __builtin_amdgcn_s_setprio(0);
    lgwait<0>();
    __builtin_amdgcn_sched_barrier(0);
    BARRIER();  // all waves' reads of buffer b complete -> safe to overwrite

    if (t + 2 < nt) STAGE(t + 2, b);  // async issue; overlaps ks1 MFMAs

    __builtin_amdgcn_s_setprio(1);
#pragma unroll
    for (int m = 0; m < 4; ++m)
#pragma unroll
      for (int n = 0; n < NF; ++n)
        acc[m][n] = __builtin_amdgcn_mfma_f32_16x16x32_bf16(af1[m], bf1[n],
                                                            acc[m][n], 0, 0, 0);
    __builtin_amdgcn_s_setprio(0);

    if (t + 1 < nt) {
      if (t + 2 < nt)
        vmwait<S>();  // only the just-issued S remain -> t+1 landed
      else
        vmwait<0>();
      BARRIER();
    }
  }

  // epilogue: C/D layout col=lane&15, row=(lane>>4)*4+reg (verified m89)
#pragma unroll
  for (int m = 0; m < 4; ++m) {
#pragma unroll
    for (int n = 0; n < NF; ++n) {
#pragma unroll
      for (int j = 0; j < 4; ++j) {
        const int r = rowBase + wr * 64 + m * 16 + lk * 4 + j;
        const int c = colBase + wc * (BNv / 2) + n * 16 + l16;
        const size_t idx = (size_t)r * N + c;
        float v = acc[m][n][j] + bias[c];
        if (EPI == 2) v = fmaxf(v, 0.f);
        if (EPI == 3) v += __bfloat162float(residb[idx]);
        C[idx] = __float2bfloat16(v);
      }
    }
  }
}

// LayerNorm over D=768 (biased variance, no eps): one wave per row.
template <bool OUTF>
__global__ __launch_bounds__(256) void ln_simple(
    const __hip_bfloat16* __restrict__ Y, __hip_bfloat16* __restrict__ outb,
    float* __restrict__ outf) {
  const int wave = threadIdx.x >> 6, lane = threadIdx.x & 63;
  const size_t base = ((size_t)blockIdx.x * 4 + wave) * 768;

  float v[12];
  float s = 0.f, q = 0.f;
#pragma unroll
  for (int c = 0; c < 3; ++c) {
    const int col = c * 256 + lane * 4;
    ushort4 a = *reinterpret_cast<const ushort4*>(&Y[base + col]);
    float y0 = bf2f(a.x), y1 = bf2f(a.y), y2 = bf2f(a.z), y3 = bf2f(a.w);
    v[c * 4 + 0] = y0; v[c * 4 + 1] = y1; v[c * 4 + 2] = y2; v[c * 4 + 3] = y3;
    s += y0 + y1 + y2 + y3;
    q += y0 * y0 + y1 * y1 + y2 * y2 + y3 * y3;
  }
#pragma unroll
  for (int off = 32; off; off >>= 1) {
    s += __shfl_xor(s, off);
    q += __shfl_xor(q, off);
  }
  const float mu = s * (1.f / 768.f);
  const float rs = rsqrtf(q * (1.f / 768.f) - mu * mu);
#pragma unroll
  for (int c = 0; c < 3; ++c) {
    const int col = c * 256 + lane * 4;
    if (OUTF) {
      float4 o;
      o.x = (v[c * 4 + 0] - mu) * rs;
      o.y = (v[c * 4 + 1] - mu) * rs;
      o.z = (v[c * 4 + 2] - mu) * rs;
      o.w = (v[c * 4 + 3] - mu) * rs;
      *reinterpret_cast<float4*>(&outf[base + col]) = o;
    } else {
      __hip_bfloat16 h0 = __float2bfloat16((v[c * 4 + 0] - mu) * rs);
      __hip_bfloat16 h1 = __float2bfloat16((v[c * 4 + 1] - mu) * rs);
      __hip_bfloat16 h2 = __float2bfloat16((v[c * 4 + 2] - mu) * rs);
      __hip_bfloat16 h3 = __float2bfloat16((v[c * 4 + 3] - mu) * rs);
      ushort4 o;
      o.x = *reinterpret_cast<unsigned short*>(&h0);
      o.y = *reinterpret_cast<unsigned short*>(&h1);
      o.z = *reinterpret_cast<unsigned short*>(&h2);
      o.w = *reinterpret_cast<unsigned short*>(&h3);
      *reinterpret_cast<ushort4*>(&outb[base + col]) = o;
    }
  }
}

// Transpose-cast tile: W (KxN fp32) -> Wt (NxK bf16); addI adds identity.
__device__ inline void tc_tile(const float* __restrict__ W,
                               __hip_bfloat16* __restrict__ Wt, int K, int N,
                               int n0, int k0, int t, bool addI) {
  __shared__ float tile[32][33];
  const int tx = t & 31;
  const int ty = t >> 5;  // 0..7
#pragma unroll
  for (int i = 0; i < 32; i += 8)
    tile[ty + i][tx] = W[(size_t)(k0 + ty + i) * N + n0 + tx];
  __syncthreads();
#pragma unroll
  for (int i = 0; i < 32; i += 8) {
    float v = tile[tx][ty + i];
    if (addI && (n0 + ty + i) == (k0 + tx)) v += 1.0f;
    Wt[(size_t)(n0 + ty + i) * K + k0 + tx] = __float2bfloat16(v);
  }
}

// Merged preprocessing: X cast [0,6144), Wv^T+I [6144,6720),
// W1^T [6720,9024), W2^T [9024,11328).
__global__ __launch_bounds__(256) void prep_kernel(
    const float* __restrict__ X, const float* __restrict__ Wv,
    const float* __restrict__ W1, const float* __restrict__ W2,
    __hip_bfloat16* __restrict__ Xb, __hip_bfloat16* __restrict__ Wvt,
    __hip_bfloat16* __restrict__ W1t, __hip_bfloat16* __restrict__ W2t) {
  const int bid = blockIdx.x;
  const int t = threadIdx.x;
  if (bid < 6144) {  // cast 8192*768 fp32 -> bf16, 4/thread
    const int i = bid * 256 + t;
    float4 v = reinterpret_cast<const float4*>(X)[i];
    __hip_bfloat16 h0 = __float2bfloat16(v.x), h1 = __float2bfloat16(v.y);
    __hip_bfloat16 h2 = __float2bfloat16(v.z), h3 = __float2bfloat16(v.w);
    ushort4 o;
    o.x = *reinterpret_cast<unsigned short*>(&h0);
    o.y = *reinterpret_cast<unsigned short*>(&h1);
    o.z = *reinterpret_cast<unsigned short*>(&h2);
    o.w = *reinterpret_cast<unsigned short*>(&h3);
    reinterpret_cast<ushort4*>(Xb)[i] = o;
  } else if (bid < 6720) {  // Wv (768x768), +I folded
    const int idx = bid - 6144;
    tc_tile(Wv, Wvt, 768, 768, (idx % 24) * 32, (idx / 24) * 32, t, true);
  } else if (bid < 9024) {  // W1 (768x3072) -> W1t (3072x768)
    const int idx = bid - 6720;
    tc_tile(W1, W1t, 768, 3072, (idx % 96) * 32, (idx / 96) * 32, t, false);
  } else {  // W2 (3072x768) -> W2t (768x3072)
    const int idx = bid - 9024;
    tc_tile(W2, W2t, 3072, 768, (idx % 24) * 32, (idx / 24) * 32, t, false);
  }
}

extern "C" void kernel_launch(void* const* d_in, const int* in_sizes, int n_in,
                              void* d_out, int out_size, void* d_ws,
                              size_t ws_size, hipStream_t stream) {
  const float* X = (const float*)d_in[0];
  const float* Wv = (const float*)d_in[5];
  const float* bv = (const float*)d_in[6];
  const float* W1 = (const float*)d_in[7];
  const float* b1 = (const float*)d_in[8];
  const float* W2 = (const float*)d_in[9];
  const float* b2 = (const float*)d_in[10];
  float* out = (float*)d_out;

  const int M = 4 * 2048; // 8192 rows
  const int D = 768, H = 3072;

  // workspace layout (round-5 proven), total 98,697,216:
  //  Xb   @ 0         (12,582,912)
  //  Wvt  @ 12582912  ( 1,179,648)
  //  W1t  @ 13762560  ( 4,718,592)
  //  W2t  @ 18481152  ( 4,718,592)
  //  Yb   @ 23199744  (12,582,912)   (reused as Y2b after LN1)
  //  X1b  @ 35782656  (12,582,912)
  //  Gb   @ 48365568  (50,331,648)
  char* ws = (char*)d_ws;
  __hip_bfloat16* Xb  = (__hip_bfloat16*)(ws);
  __hip_bfloat16* Wvt = (__hip_bfloat16*)(ws + 12582912);
  __hip_bfloat16* W1t = (__hip_bfloat16*)(ws + 13762560);
  __hip_bfloat16* W2t = (__hip_bfloat16*)(ws + 18481152);
  __hip_bfloat16* Yb  = (__hip_bfloat16*)(ws + 23199744);
  __hip_bfloat16* X1b = (__hip_bfloat16*)(ws + 35782656);
  __hip_bfloat16* Gb  = (__hip_bfloat16*)(ws + 48365568);
  __hip_bfloat16* Y2b = Yb;  // Yb dead after LN1

  prep_kernel<<<11328, 256, 0, stream>>>(X, Wv, W1, W2, Xb, Wvt, W1t, W2t);

  // Y = X@(Wv+I) + bv  (residual folded into weight), grid 64*8 = 512
  gemm128<96, 4><<<512, 256, 0, stream>>>(Xb, Wvt, Yb, bv, nullptr, M, D, D);
  // X1 = LN(Y)
  ln_simple<false><<<M / 4, 256, 0, stream>>>(Yb, X1b, nullptr);
  // G = relu(X1@W1 + b1), BN=192: grid 64*16 = 1024 (2 exact rounds)
  gemm128<192, 2><<<1024, 256, 0, stream>>>(X1b, W1t, Gb, b1, nullptr, M, H, D);
  // Y2 = G@W2 + b2 + X1 (fused residual), grid 64*8 = 512, nt = 48
  gemm128<96, 3><<<512, 256, 0, stream>>>(Gb, W2t, Y2b, b2, X1b, M, D, H);
  // out = LN(Y2)
  ln_simple<true><<<M / 4, 256, 0, stream>>>(Y2b, nullptr, out);
}